// Round 4
// baseline (30.153 us; speedup 1.0000x reference)
//
#include <hip/hip_runtime.h>

constexpr int BLK = 512;        // 8 waves
constexpr int NPB = 512;        // points per block
constexpr int CH  = NPB / 64;   // chunks per wave

// ---------- activations (fast fp32, native transcendentals) ----------
__device__ __forceinline__ float fast_rcp(float x) { return __builtin_amdgcn_rcpf(x); }

__device__ __forceinline__ float fast_tanh(float x) {
    float e = __expf(-2.0f * fabsf(x));
    float t = 1.0f - 2.0f * e * fast_rcp(1.0f + e);
    return copysignf(t, x);
}

template<int A> __device__ __forceinline__ float act_fn(float x);
template<> __device__ __forceinline__ float act_fn<0>(float x) { return fmaxf(x, 0.0f); }   // relu
template<> __device__ __forceinline__ float act_fn<1>(float x) { return fast_tanh(x); }     // tanh
template<> __device__ __forceinline__ float act_fn<2>(float x) {                            // elu
    return x > 0.0f ? x : (__expf(x) - 1.0f);
}
template<> __device__ __forceinline__ float act_fn<3>(float x) {                            // silu
    return x * fast_rcp(1.0f + __expf(-x));
}
template<> __device__ __forceinline__ float act_fn<4>(float x) {                            // gelu (tanh approx)
    float u = 0.7978845608028654f * fmaf(0.044715f * x, x * x, x);
    return 0.5f * x * (1.0f + fast_tanh(u));
}
template<> __device__ __forceinline__ float act_fn<5>(float x) { return x; }                // none
template<> __device__ __forceinline__ float act_fn<6>(float x) {                            // selu
    const float sc = 1.0507009873554805f;
    const float al = 1.6732632423543772f;
    return x > 0.0f ? sc * x : (sc * al) * (__expf(x) - 1.0f);
}
template<> __device__ __forceinline__ float act_fn<7>(float x) {                            // softplus
    return fmaxf(x, 0.0f) + __logf(1.0f + __expf(-fabsf(x)));
}

// ---------- one wave = one expert over the block's NPB points ----------
template<int A>
__device__ __forceinline__ void run_wave(const float* __restrict__ s_re,
                                         const float* __restrict__ s_im,
                                         const float* __restrict__ s_am,
                                         float* __restrict__ s_row,   // this wave's partial row
                                         const float* wre, const float* wim,
                                         const float* wam, const float* bb,
                                         const float* w2, int lane) {
#pragma unroll 2
    for (int c = 0; c < CH; ++c) {
        const int idx = c * 64 + lane;
        const float re = s_re[idx];
        const float im = s_im[idx];
        const float am = s_am[idx];
        float acc = 0.0f;
#pragma unroll
        for (int h = 0; h < 16; ++h) {
            float z = fmaf(re, wre[h], fmaf(im, wim[h], fmaf(am, wam[h], bb[h])));
            acc = fmaf(act_fn<A>(z), w2[h], acc);
        }
        s_row[idx] = acc;   // ew already folded into w2
    }
}

__global__ __launch_bounds__(BLK)
void moe_kernel(const float* __restrict__ x,
                const float* __restrict__ W1,
                const float* __restrict__ b1,
                const float* __restrict__ W2,
                const float* __restrict__ b2,
                const float* __restrict__ ew,
                float* __restrict__ out, int npts) {
    __shared__ float s_re[NPB], s_im[NPB], s_am[NPB], s_base[NPB];
    __shared__ float s_part[8][NPB];

    const int tid = threadIdx.x;
    const int p0  = blockIdx.x * NPB;

    // ---- staging: one point per thread; also fold the 4 analytic experts ----
    {
        const int p = p0 + tid;
        float2 v = (p < npts) ? reinterpret_cast<const float2*>(x)[p]
                              : make_float2(0.0f, 0.0f);
        const float am = __builtin_amdgcn_sqrtf(fmaf(v.x, v.x, v.y * v.y));
        s_re[tid] = v.x;
        s_im[tid] = v.y;
        s_am[tid] = am;
        float bconst = 0.0f;
#pragma unroll
        for (int i = 0; i < 8; ++i) bconst = fmaf(ew[i], b2[i], bconst);
        float a = fmaf(ew[8], fabsf(v.x) + fabsf(v.y), bconst);  // 'abs' + folded b2
        a = fmaf(ew[9], am, a);                                  // 'modulus'
        a = fmaf(ew[10], __sinf(am), a);                         // 'sin'
        a = fmaf(ew[11], __cosf(am), a);                         // 'cos'
        s_base[tid] = a;
    }
    __syncthreads();

    // ---- per-wave expert: weights loaded ONCE (wave-uniform -> scalar regs) ----
    const int wid  = __builtin_amdgcn_readfirstlane(tid >> 6);
    const int lane = tid & 63;
    // wave->expert remap so per-SIMD (waves w, w+4) transcendental load balances:
    // SIMD0: tanh+relu, SIMD1: softplus+none, SIMD2: silu+elu, SIMD3: gelu+selu
    constexpr int EXP_OF_WAVE[8] = {1, 7, 3, 4, 0, 5, 2, 6};
    const int e = EXP_OF_WAVE[wid];

    float wre[16], wim[16], wam[16], bb[16], w2[16];
    const float ewI = ew[e];
#pragma unroll
    for (int h = 0; h < 16; ++h) {
        wre[h] = W1[e * 48 + h];         // W1: (8,3,16)
        wim[h] = W1[e * 48 + 16 + h];
        wam[h] = W1[e * 48 + 32 + h];
        bb[h]  = b1[e * 16 + h];
        w2[h]  = W2[e * 16 + h] * ewI;   // fold expert weight
    }

    float* s_row = &s_part[wid][0];
    switch (e) {
        case 0: run_wave<0>(s_re, s_im, s_am, s_row, wre, wim, wam, bb, w2, lane); break;
        case 1: run_wave<1>(s_re, s_im, s_am, s_row, wre, wim, wam, bb, w2, lane); break;
        case 2: run_wave<2>(s_re, s_im, s_am, s_row, wre, wim, wam, bb, w2, lane); break;
        case 3: run_wave<3>(s_re, s_im, s_am, s_row, wre, wim, wam, bb, w2, lane); break;
        case 4: run_wave<4>(s_re, s_im, s_am, s_row, wre, wim, wam, bb, w2, lane); break;
        case 5: run_wave<5>(s_re, s_im, s_am, s_row, wre, wim, wam, bb, w2, lane); break;
        case 6: run_wave<6>(s_re, s_im, s_am, s_row, wre, wim, wam, bb, w2, lane); break;
        case 7: run_wave<7>(s_re, s_im, s_am, s_row, wre, wim, wam, bb, w2, lane); break;
    }
    __syncthreads();

    // ---- reduce: 8 partial rows + analytic base -> output ----
    {
        const int p = p0 + tid;
        if (p < npts) {
            float s = s_base[tid];
#pragma unroll
            for (int w = 0; w < 8; ++w) s += s_part[w][tid];
            out[p] = s;
        }
    }
}

extern "C" void kernel_launch(void* const* d_in, const int* in_sizes, int n_in,
                              void* d_out, int out_size, void* d_ws, size_t ws_size,
                              hipStream_t stream) {
    const float* x  = (const float*)d_in[0];
    const float* W1 = (const float*)d_in[1];
    const float* b1 = (const float*)d_in[2];
    const float* W2 = (const float*)d_in[3];
    const float* b2 = (const float*)d_in[4];
    const float* ew = (const float*)d_in[5];
    float* out = (float*)d_out;

    const int npts = in_sizes[0] / 2;  // (B,S,C,2) -> B*S*C points
    const int blocks = (npts + NPB - 1) / NPB;
    hipLaunchKernelGGL(moe_kernel, dim3(blocks), dim3(BLK), 0, stream,
                       x, W1, b1, W2, b2, ew, out, npts);
}

// Round 5
// 24.045 us; speedup vs baseline: 1.2540x; 1.2540x over previous
//
#include <hip/hip_runtime.h>

constexpr int BLK = 256;
constexpr int P   = 2;     // adjacent points per thread

// ---------- activations (fast fp32, native transcendentals) ----------
__device__ __forceinline__ float fast_rcp(float x) { return __builtin_amdgcn_rcpf(x); }

template<int A> __device__ __forceinline__ float act_fn(float x);
// 0: relu
template<> __device__ __forceinline__ float act_fn<0>(float x) { return fmaxf(x, 0.0f); }
// 1: tanh = 1 - 2/(1+e^{2x})  (inf-safe: rcp(inf)=0)
template<> __device__ __forceinline__ float act_fn<1>(float x) {
    float e = __expf(2.0f * x);
    return fmaf(-2.0f, fast_rcp(1.0f + e), 1.0f);
}
// 2: elu (alpha=1)
template<> __device__ __forceinline__ float act_fn<2>(float x) {
    return x > 0.0f ? x : (__expf(x) - 1.0f);
}
// 3: silu = x * sigmoid(x)
template<> __device__ __forceinline__ float act_fn<3>(float x) {
    return x * fast_rcp(1.0f + __expf(-x));
}
// 4: gelu ~= x * sigmoid(1.702 x)  (max abs err ~0.02, x1/12 weight -> <2e-3)
template<> __device__ __forceinline__ float act_fn<4>(float x) {
    return x * fast_rcp(1.0f + __expf(-1.702f * x));
}
// 5: identity
template<> __device__ __forceinline__ float act_fn<5>(float x) { return x; }
// 6: selu
template<> __device__ __forceinline__ float act_fn<6>(float x) {
    const float sc   = 1.0507009873554805f;
    const float scal = 1.7580993408473766f;   // sc * alpha
    float n = fmaf(scal, __expf(x), -scal);   // sc*al*(e^x - 1)
    return x > 0.0f ? sc * x : n;
}
// 7: softplus = max(x,0) + log1p(e^{-|x|})
template<> __device__ __forceinline__ float act_fn<7>(float x) {
    return fmaxf(x, 0.0f) + __logf(1.0f + __expf(-fabsf(x)));
}

// ---------- one expert, compile-time index A -> all weight reads uniform (s_load) ----------
template<int A>
__device__ __forceinline__ void run_expert(const float* __restrict__ W1,
                                           const float* __restrict__ b1,
                                           const float* __restrict__ W2,
                                           const float* __restrict__ ew,
                                           const float* re, const float* im,
                                           const float* am, float* acc) {
    float accE[P];
#pragma unroll
    for (int k = 0; k < P; ++k) accE[k] = 0.0f;

#pragma unroll
    for (int h = 0; h < 16; ++h) {
        // compile-time offsets from kernel-arg bases -> scalar loads, no VGPR cost
        const float wre = W1[A * 48 + h];        // W1: (8,3,16)
        const float wim = W1[A * 48 + 16 + h];
        const float wam = W1[A * 48 + 32 + h];
        const float bb  = b1[A * 16 + h];
        const float w2  = W2[A * 16 + h];
#pragma unroll
        for (int k = 0; k < P; ++k) {
            float z = fmaf(re[k], wre, fmaf(im[k], wim, fmaf(am[k], wam, bb)));
            accE[k] = fmaf(act_fn<A>(z), w2, accE[k]);
        }
    }
    const float ewI = ew[A];
#pragma unroll
    for (int k = 0; k < P; ++k) acc[k] = fmaf(accE[k], ewI, acc[k]);
    __builtin_amdgcn_sched_barrier(0);   // bound the scheduling window per expert
}

__global__ __launch_bounds__(BLK, 4)
void moe_kernel(const float* __restrict__ x,
                const float* __restrict__ W1,
                const float* __restrict__ b1,
                const float* __restrict__ W2,
                const float* __restrict__ b2,
                const float* __restrict__ ew,
                float* __restrict__ out, int npts) {
    const int p0 = blockIdx.x * (BLK * P) + threadIdx.x * P;
    if (p0 >= npts) return;

    float bconst = 0.0f;
#pragma unroll
    for (int i = 0; i < 8; ++i) bconst = fmaf(ew[i], b2[i], bconst);
    const float ewA = ew[8], ewM = ew[9], ewS = ew[10], ewC = ew[11];

    // two adjacent points: one float4 load (16B/lane, coalesced)
    float4 v = reinterpret_cast<const float4*>(x)[p0 >> 1];
    float re[P] = {v.x, v.z};
    float im[P] = {v.y, v.w};
    float am[P], acc[P];

#pragma unroll
    for (int k = 0; k < P; ++k) {
        am[k] = __builtin_amdgcn_sqrtf(fmaf(re[k], re[k], im[k] * im[k]));
        float a = fmaf(ewA, fabsf(re[k]) + fabsf(im[k]), bconst);  // 'abs' + folded b2
        a = fmaf(ewM, am[k], a);                                   // 'modulus'
        a = fmaf(ewS, __sinf(am[k]), a);                           // 'sin'
        a = fmaf(ewC, __cosf(am[k]), a);                           // 'cos'
        acc[k] = a;
    }

    run_expert<0>(W1, b1, W2, ew, re, im, am, acc);  // relu
    run_expert<1>(W1, b1, W2, ew, re, im, am, acc);  // tanh
    run_expert<2>(W1, b1, W2, ew, re, im, am, acc);  // elu
    run_expert<3>(W1, b1, W2, ew, re, im, am, acc);  // silu
    run_expert<4>(W1, b1, W2, ew, re, im, am, acc);  // gelu (sigmoid form)
    run_expert<5>(W1, b1, W2, ew, re, im, am, acc);  // none
    run_expert<6>(W1, b1, W2, ew, re, im, am, acc);  // selu
    run_expert<7>(W1, b1, W2, ew, re, im, am, acc);  // softplus

    reinterpret_cast<float2*>(out)[p0 >> 1] = make_float2(acc[0], acc[1]);
}

extern "C" void kernel_launch(void* const* d_in, const int* in_sizes, int n_in,
                              void* d_out, int out_size, void* d_ws, size_t ws_size,
                              hipStream_t stream) {
    const float* x  = (const float*)d_in[0];
    const float* W1 = (const float*)d_in[1];
    const float* b1 = (const float*)d_in[2];
    const float* W2 = (const float*)d_in[3];
    const float* b2 = (const float*)d_in[4];
    const float* ew = (const float*)d_in[5];
    float* out = (float*)d_out;

    const int npts = in_sizes[0] / 2;  // (B,S,C,2) -> B*S*C points
    const int blocks = (npts + BLK * P - 1) / (BLK * P);
    hipLaunchKernelGGL(moe_kernel, dim3(blocks), dim3(BLK), 0, stream,
                       x, W1, b1, W2, b2, ew, out, npts);
}

// Round 6
// 20.093 us; speedup vs baseline: 1.5007x; 1.1967x over previous
//
#include <hip/hip_runtime.h>

constexpr int BLK = 256;
constexpr int P   = 2;     // adjacent points per thread (one packed pair)

typedef float v2f __attribute__((ext_vector_type(2)));

__device__ __forceinline__ v2f splat(float s) { return (v2f){s, s}; }
__device__ __forceinline__ v2f pk_fma(v2f a, v2f b, v2f c) {
    return __builtin_elementwise_fma(a, b, c);
}
__device__ __forceinline__ v2f pk_max0(v2f a) {
    return __builtin_elementwise_max(a, (v2f){0.0f, 0.0f});
}

// ---------- native transcendentals ----------
__device__ __forceinline__ float fast_rcp(float x) { return __builtin_amdgcn_rcpf(x); }

__device__ __forceinline__ float fast_exp2(float x) {
#if __has_builtin(__builtin_amdgcn_exp2f)
    return __builtin_amdgcn_exp2f(x);
#else
    return __expf(x * 0.6931471805599453f);
#endif
}
__device__ __forceinline__ float fast_log2(float x) {
#if __has_builtin(__builtin_amdgcn_logf)
    return __builtin_amdgcn_logf(x);
#else
    return __log2f(x);
#endif
}

#define LOG2E 1.4426950408889634f
#define LN2   0.6931471805599453f

// component-wise trans on a pair
__device__ __forceinline__ v2f pk_exp2(v2f t) { return (v2f){fast_exp2(t.x), fast_exp2(t.y)}; }
__device__ __forceinline__ v2f pk_rcp(v2f t)  { return (v2f){fast_rcp(t.x),  fast_rcp(t.y)};  }

// ---------- activations on a packed pair ----------
template<int A> __device__ __forceinline__ v2f act2(v2f z);
// 0: relu
template<> __device__ __forceinline__ v2f act2<0>(v2f z) { return pk_max0(z); }
// 1: tanh = 1 - 2*rcp(1+2^{2*log2e*z})
template<> __device__ __forceinline__ v2f act2<1>(v2f z) {
    v2f e = pk_exp2(z * (2.0f * LOG2E));
    v2f r = pk_rcp(e + 1.0f);
    return pk_fma(splat(-2.0f), r, splat(1.0f));
}
// 2: elu
template<> __device__ __forceinline__ v2f act2<2>(v2f z) {
    v2f em = pk_exp2(z * LOG2E) - 1.0f;
    v2f r;
    r.x = z.x > 0.0f ? z.x : em.x;
    r.y = z.y > 0.0f ? z.y : em.y;
    return r;
}
// 3: silu = z * rcp(1+2^{-log2e*z})
template<> __device__ __forceinline__ v2f act2<3>(v2f z) {
    v2f e = pk_exp2(z * (-LOG2E));
    return z * pk_rcp(e + 1.0f);
}
// 4: gelu ~= z * sigmoid(1.702 z)
template<> __device__ __forceinline__ v2f act2<4>(v2f z) {
    v2f e = pk_exp2(z * (-1.702f * LOG2E));
    return z * pk_rcp(e + 1.0f);
}
// 5: none
template<> __device__ __forceinline__ v2f act2<5>(v2f z) { return z; }
// 6: selu
template<> __device__ __forceinline__ v2f act2<6>(v2f z) {
    const float sc   = 1.0507009873554805f;
    const float scal = 1.7580993408473766f;   // sc*alpha
    v2f e = pk_exp2(z * LOG2E);
    v2f n = pk_fma(splat(scal), e, splat(-scal));
    v2f p = z * sc;
    v2f r;
    r.x = z.x > 0.0f ? p.x : n.x;
    r.y = z.y > 0.0f ? p.y : n.y;
    return r;
}
// 7: softplus = max(z,0) + ln2*log2(1+2^{-log2e*|z|})
template<> __device__ __forceinline__ v2f act2<7>(v2f z) {
    v2f a = __builtin_elementwise_abs(z) * (-LOG2E);
    v2f d = pk_exp2(a) + 1.0f;
    v2f l = (v2f){fast_log2(d.x), fast_log2(d.y)};
    return pk_fma(splat(LN2), l, pk_max0(z));
}

// ---------- one expert, compile-time index A -> all weight reads uniform (s_load) ----------
template<int A>
__device__ __forceinline__ void run_expert(const float* __restrict__ W1,
                                           const float* __restrict__ b1,
                                           const float* __restrict__ W2,
                                           const float* __restrict__ ew,
                                           v2f re, v2f im, v2f am, v2f& acc) {
    v2f accE = (v2f){0.0f, 0.0f};
#pragma unroll
    for (int h = 0; h < 16; ++h) {
        const float wre = W1[A * 48 + h];        // W1: (8,3,16)
        const float wim = W1[A * 48 + 16 + h];
        const float wam = W1[A * 48 + 32 + h];
        const float bb  = b1[A * 16 + h];
        const float w2  = W2[A * 16 + h];
        v2f z = pk_fma(re, splat(wre),
                pk_fma(im, splat(wim),
                pk_fma(am, splat(wam), splat(bb))));
        accE = pk_fma(act2<A>(z), splat(w2), accE);
    }
    acc = pk_fma(accE, splat(ew[A]), acc);
    __builtin_amdgcn_sched_barrier(0);   // bound the scheduling window per expert
}

__global__ __launch_bounds__(BLK, 4)
void moe_kernel(const float* __restrict__ x,
                const float* __restrict__ W1,
                const float* __restrict__ b1,
                const float* __restrict__ W2,
                const float* __restrict__ b2,
                const float* __restrict__ ew,
                float* __restrict__ out, int npts) {
    const int pr = blockIdx.x * BLK + threadIdx.x;   // pair index
    if (pr * P >= npts) return;

    float bconst = 0.0f;
#pragma unroll
    for (int i = 0; i < 8; ++i) bconst = fmaf(ew[i], b2[i], bconst);

    // two adjacent points: one float4 load (16B/lane, coalesced)
    float4 v = reinterpret_cast<const float4*>(x)[pr];
    v2f re = (v2f){v.x, v.z};
    v2f im = (v2f){v.y, v.w};
    v2f r2 = pk_fma(re, re, im * im);
    v2f am = (v2f){__builtin_amdgcn_sqrtf(r2.x), __builtin_amdgcn_sqrtf(r2.y)};

    // analytic experts + folded b2 bias
    v2f acc = pk_fma(splat(ew[8]),
                     __builtin_elementwise_abs(re) + __builtin_elementwise_abs(im),
                     splat(bconst));                              // 'abs'
    acc = pk_fma(splat(ew[9]), am, acc);                          // 'modulus'
    acc = pk_fma(splat(ew[10]), (v2f){__sinf(am.x), __sinf(am.y)}, acc);  // 'sin'
    acc = pk_fma(splat(ew[11]), (v2f){__cosf(am.x), __cosf(am.y)}, acc);  // 'cos'

    run_expert<0>(W1, b1, W2, ew, re, im, am, acc);  // relu
    run_expert<1>(W1, b1, W2, ew, re, im, am, acc);  // tanh
    run_expert<2>(W1, b1, W2, ew, re, im, am, acc);  // elu
    run_expert<3>(W1, b1, W2, ew, re, im, am, acc);  // silu
    run_expert<4>(W1, b1, W2, ew, re, im, am, acc);  // gelu (sigmoid form)
    run_expert<5>(W1, b1, W2, ew, re, im, am, acc);  // none
    run_expert<6>(W1, b1, W2, ew, re, im, am, acc);  // selu
    run_expert<7>(W1, b1, W2, ew, re, im, am, acc);  // softplus

    reinterpret_cast<float2*>(out)[pr] = make_float2(acc.x, acc.y);
}

extern "C" void kernel_launch(void* const* d_in, const int* in_sizes, int n_in,
                              void* d_out, int out_size, void* d_ws, size_t ws_size,
                              hipStream_t stream) {
    const float* x  = (const float*)d_in[0];
    const float* W1 = (const float*)d_in[1];
    const float* b1 = (const float*)d_in[2];
    const float* W2 = (const float*)d_in[3];
    const float* b2 = (const float*)d_in[4];
    const float* ew = (const float*)d_in[5];
    float* out = (float*)d_out;

    const int npts = in_sizes[0] / 2;  // (B,S,C,2) -> B*S*C points
    const int blocks = (npts + BLK * P - 1) / (BLK * P);
    hipLaunchKernelGGL(moe_kernel, dim3(blocks), dim3(BLK), 0, stream,
                       x, W1, b1, W2, b2, ew, out, npts);
}